// Round 4
// baseline (51.288 us; speedup 1.0000x reference)
//
#include <hip/hip_runtime.h>
#include <math.h>

// LearnedDRoPEEnergy: B=16, K=256, H=W=64, T=1.0
#define NPOS   65536        // B*H*W
#define NWORDS 8            // K/32
#define LUT_FLOATS (32*256) // 8192 floats = 32 KB
#define PACK_BYTES (NPOS * NWORDS * 4)  // 2 MB

typedef float floatx4 __attribute__((ext_vector_type(4)));  // clang-native, ok for nontemporal builtins

// 8 representative offsets (other 8 are negatives; d and gate symmetric,
// torus sum translation-invariant -> multiply by 2). Verified R1/R2 absmax=0.
__device__ __constant__ int c_dy8[8] = {-1, 0, -1, -1, -2,  0, -2, -2};
__device__ __constant__ int c_dx8[8] = { 0,-1, -1,  1,  0, -2, -2,  2};

// Kernel A: pack z bitplanes, byte-granular so each block's reads are fully
// sequential 4KB runs at FULL occupancy (2048 blocks, 8 blocks/CU).
// Block beta<2048: (b, g, q) with g = byte-group (k/8), q = quarter-plane.
// Reads 8 k-planes' q-quarter (8 x 4KB, coalesced float4, nontemporal),
// accumulates bit j for 4 positions, stores 4 bytes.
// Block 2048: builds global LUT + zeroes d_out.
__global__ __launch_bounds__(256) void pack_kernel(const float* __restrict__ z,
                                                   unsigned char* __restrict__ pbytes,
                                                   float* __restrict__ gLUT,
                                                   const float* __restrict__ w_logit,
                                                   float* __restrict__ out) {
    int tid = threadIdx.x;
    unsigned beta = blockIdx.x;
    if (beta == 2048) {
        // gLUT[g*256+v] = sum over set bits j of v of softplus(w_logit[g*8+j])
        int p = tid >> 3;              // 0..31
        int vbase = (tid & 7) * 32;
        float wv[8];
#pragma unroll
        for (int j = 0; j < 8; ++j) {
            float x = w_logit[p * 8 + j];
            wv[j] = log1pf(expf(x));   // softplus, fp32
        }
        for (int v = vbase; v < vbase + 32; ++v) {
            float s = 0.0f;
#pragma unroll
            for (int j = 0; j < 8; ++j) s += ((v >> j) & 1) ? wv[j] : 0.0f;
            gLUT[p * 256 + v] = s;
        }
        if (tid < 16) out[tid] = 0.0f;
        return;
    }
    int b = beta >> 7;                 // 16
    int g = (beta >> 2) & 31;          // 32 byte-groups (k = 8g..8g+7)
    int q = beta & 3;                  // quarter of the 4096-wide hw plane
    const float* base = z + ((size_t)(b * 256 + g * 8) * 4096) + q * 1024 + tid * 4;
    unsigned a0 = 0, a1 = 0, a2 = 0, a3 = 0;
#pragma unroll
    for (int j = 0; j < 8; ++j) {
        floatx4 v = __builtin_nontemporal_load((const floatx4*)(base + (size_t)j * 4096));
        unsigned bit = 1u << j;
        if (v.x != 0.0f) a0 |= bit;
        if (v.y != 0.0f) a1 |= bit;
        if (v.z != 0.0f) a2 |= bit;
        if (v.w != 0.0f) a3 |= bit;
    }
    // byte layout == little-endian dword layout pack[pos*8 + word]: byte g of
    // the 32B record holds k = 8g..8g+7 (exactly what the energy LUT expects)
    size_t pos0 = (size_t)b * 4096 + q * 1024 + tid * 4;
    pbytes[(pos0 + 0) * 32 + g] = (unsigned char)a0;
    pbytes[(pos0 + 1) * 32 + g] = (unsigned char)a1;
    pbytes[(pos0 + 2) * 32 + g] = (unsigned char)a2;
    pbytes[(pos0 + 3) * 32 + g] = (unsigned char)a3;
}

// Kernel B: one thread per (position, offset) pair. 2048 blocks x 256.
// Stage LUT global->LDS, then 8 XOR + 32 byte-LUT lookups per pair.
__global__ __launch_bounds__(256) void energy_kernel(const uint4* __restrict__ pk,
                                                     const float* __restrict__ gLUT,
                                                     const float* __restrict__ tau_p,
                                                     float* __restrict__ out) {
    __shared__ float wtab[LUT_FLOATS];   // 32 KB
    __shared__ float red[4];
    int tid = threadIdx.x;

    // stage LUT: 8 x float4 per thread, coalesced (all L2 hits)
#pragma unroll
    for (int i = 0; i < 8; ++i) {
        int idx = (i * 256 + tid) * 4;
        *(float4*)(&wtab[idx]) = *(const float4*)(&gLUT[idx]);
    }
    __syncthreads();

    float tau = tau_p[0];
    int t   = blockIdx.x * 256 + tid;    // 0 .. 524287
    int o   = t >> 16;                   // 0..7, uniform per block
    int pos = t & 65535;
    int b = pos >> 12;
    int h = (pos >> 6) & 63;
    int w = pos & 63;

    uint4 c0 = pk[pos * 2 + 0];
    uint4 c1 = pk[pos * 2 + 1];
    int h2 = (h + c_dy8[o]) & 63;
    int w2 = (w + c_dx8[o]) & 63;
    int np = (b << 12) | (h2 << 6) | w2;
    uint4 n0 = pk[np * 2 + 0];
    uint4 n1 = pk[np * 2 + 1];

    unsigned x[8];
    x[0] = c0.x ^ n0.x; x[1] = c0.y ^ n0.y; x[2] = c0.z ^ n0.z; x[3] = c0.w ^ n0.w;
    x[4] = c1.x ^ n1.x; x[5] = c1.y ^ n1.y; x[6] = c1.z ^ n1.z; x[7] = c1.w ^ n1.w;

    float d0 = 0.0f, d1 = 0.0f;
#pragma unroll
    for (int i = 0; i < 8; ++i) {
        unsigned xi = x[i];
        d0 += wtab[(i * 4 + 0) * 256 + (xi & 255)];
        d1 += wtab[(i * 4 + 1) * 256 + ((xi >> 8) & 255)];
        d0 += wtab[(i * 4 + 2) * 256 + ((xi >> 16) & 255)];
        d1 += wtab[(i * 4 + 3) * 256 + (xi >> 24)];
    }
    float d = d0 + d1;
    // gate*d = d / (1 + exp(d - tau)); exp overflow -> inf -> 0, correct limit
    float e = d / (1.0f + expf(d - tau));

    // block reduction (b uniform per block), one atomic, x2 for symmetry
#pragma unroll
    for (int s = 32; s > 0; s >>= 1) e += __shfl_down(e, s, 64);
    int lane = tid & 63, wv = tid >> 6;
    if (lane == 0) red[wv] = e;
    __syncthreads();
    if (tid == 0) atomicAdd(out + b, 2.0f * (red[0] + red[1] + red[2] + red[3]));
}

extern "C" void kernel_launch(void* const* d_in, const int* in_sizes, int n_in,
                              void* d_out, int out_size, void* d_ws, size_t ws_size,
                              hipStream_t stream) {
    const float* z       = (const float*)d_in[0];   // (B,K,H,W) fp32 0/1
    const float* w_logit = (const float*)d_in[1];   // (K,)
    const float* tau     = (const float*)d_in[2];   // scalar
    float* out = (float*)d_out;                     // (B,)
    unsigned char* pack = (unsigned char*)d_ws;     // 2 MB
    float* gLUT = (float*)((char*)d_ws + PACK_BYTES); // +32 KB

    hipLaunchKernelGGL(pack_kernel, dim3(2049), dim3(256), 0, stream,
                       z, pack, gLUT, w_logit, out);
    hipLaunchKernelGGL(energy_kernel, dim3(2048), dim3(256), 0, stream,
                       (const uint4*)pack, gLUT, tau, out);
}

// Round 5
// 47.059 us; speedup vs baseline: 1.0899x; 1.0899x over previous
//
#include <hip/hip_runtime.h>
#include <math.h>

// LearnedDRoPEEnergy: B=16, K=256, H=W=64, T=1.0
#define NPOS   65536            // B*H*W
#define LUT_FLOATS (32*256)     // 8192 floats = 32 KB
#define PACKW_BYTES (8 * NPOS * 4)  // word-major pack: packw[word][pos], 2 MB

// 8 representative offsets (other 8 are negatives; d and gate symmetric,
// torus sum translation-invariant -> multiply by 2). Verified R1/R2/R4 absmax=0.
__device__ __constant__ int c_dy8[8] = {-1, 0, -1, -1, -2,  0, -2, -2};
__device__ __constant__ int c_dx8[8] = { 0,-1, -1,  1,  0, -2, -2,  2};

// Kernel A: register-accumulated bitplane pack, word-major output.
// Thread (q, pos): reads 64 k-planes (quarter q) at z[b][k][hw] -- lane l maps
// to position pos0+l so every load is a 256B-coalesced wave read -- ORs bits
// into 2 register words, stores 2 fully-coalesced dwords to packw[word][pos].
// No scattered stores, no cross-XCD record assembly. Block 1024: LUT + out=0.
__global__ __launch_bounds__(256) void pack_kernel(const float* __restrict__ z,
                                                   unsigned* __restrict__ packw,
                                                   float* __restrict__ gLUT,
                                                   const float* __restrict__ w_logit,
                                                   float* __restrict__ out) {
    int tid = threadIdx.x;
    unsigned beta = blockIdx.x;
    if (beta == 1024) {
        // gLUT[p*256+v] = sum over set bits j of v of softplus(w_logit[p*8+j])
        int p = tid >> 3;              // 0..31
        int vbase = (tid & 7) * 32;
        float wv[8];
#pragma unroll
        for (int j = 0; j < 8; ++j) {
            float x = w_logit[p * 8 + j];
            wv[j] = log1pf(expf(x));   // softplus, fp32
        }
        for (int v = vbase; v < vbase + 32; ++v) {
            float s = 0.0f;
#pragma unroll
            for (int j = 0; j < 8; ++j) s += ((v >> j) & 1) ? wv[j] : 0.0f;
            gLUT[p * 256 + v] = s;
        }
        if (tid < 16) out[tid] = 0.0f;
        return;
    }
    int t   = beta * 256 + tid;        // 0 .. 262143
    int q   = t >> 16;                 // k-quarter 0..3 (k = 64q .. 64q+63)
    int pos = t & 65535;
    int b   = pos >> 12;
    int hw  = pos & 4095;
    const float* base = z + ((size_t)(b * 256 + q * 64) << 12) + hw;
    unsigned a0 = 0, a1 = 0;
#pragma unroll
    for (int j = 0; j < 32; ++j) {
        float v0 = __builtin_nontemporal_load(base + ((size_t)j << 12));
        float v1 = __builtin_nontemporal_load(base + ((size_t)(j + 32) << 12));
        if (v0 != 0.0f) a0 |= (1u << j);
        if (v1 != 0.0f) a1 |= (1u << j);
    }
    packw[(q * 2 + 0) * NPOS + pos] = a0;   // coalesced dword store
    packw[(q * 2 + 1) * NPOS + pos] = a1;
}

// Kernel B: one thread per (position, offset) pair. 2048 blocks x 256.
// Word-major coalesced L2-hit loads, 32 byte-LUT LDS gathers, gate, reduce.
__global__ __launch_bounds__(256) void energy_kernel(const unsigned* __restrict__ pw,
                                                     const float* __restrict__ gLUT,
                                                     const float* __restrict__ tau_p,
                                                     float* __restrict__ out) {
    __shared__ float wtab[LUT_FLOATS];   // 32 KB
    __shared__ float red[4];
    int tid = threadIdx.x;

    // stage LUT: 8 x float4 per thread, coalesced
#pragma unroll
    for (int i = 0; i < 8; ++i) {
        int idx = (i * 256 + tid) * 4;
        *(float4*)(&wtab[idx]) = *(const float4*)(&gLUT[idx]);
    }
    __syncthreads();

    float tau = tau_p[0];
    int t   = blockIdx.x * 256 + tid;    // 0 .. 524287
    int o   = t >> 16;                   // 0..7, uniform per block
    int pos = t & 65535;
    int b = pos >> 12;
    int h = (pos >> 6) & 63;
    int w = pos & 63;

    int h2 = (h + c_dy8[o]) & 63;
    int w2 = (w + c_dx8[o]) & 63;
    int np = (b << 12) | (h2 << 6) | w2;

    unsigned x[8];
#pragma unroll
    for (int wd = 0; wd < 8; ++wd) {
        unsigned c = pw[wd * NPOS + pos];   // coalesced (consecutive pos)
        unsigned n = pw[wd * NPOS + np];    // coalesced (shifted run)
        x[wd] = c ^ n;
    }

    float d0 = 0.0f, d1 = 0.0f;
#pragma unroll
    for (int i = 0; i < 8; ++i) {
        unsigned xi = x[i];
        d0 += wtab[(i * 4 + 0) * 256 + (xi & 255)];
        d1 += wtab[(i * 4 + 1) * 256 + ((xi >> 8) & 255)];
        d0 += wtab[(i * 4 + 2) * 256 + ((xi >> 16) & 255)];
        d1 += wtab[(i * 4 + 3) * 256 + (xi >> 24)];
    }
    float d = d0 + d1;
    // gate*d = d / (1 + exp(d - tau)); exp overflow -> inf -> 0, correct limit
    float e = d / (1.0f + expf(d - tau));

    // block reduction (b uniform per block), one atomic, x2 for symmetry
#pragma unroll
    for (int s = 32; s > 0; s >>= 1) e += __shfl_down(e, s, 64);
    int lane = tid & 63, wv = tid >> 6;
    if (lane == 0) red[wv] = e;
    __syncthreads();
    if (tid == 0) atomicAdd(out + b, 2.0f * (red[0] + red[1] + red[2] + red[3]));
}

extern "C" void kernel_launch(void* const* d_in, const int* in_sizes, int n_in,
                              void* d_out, int out_size, void* d_ws, size_t ws_size,
                              hipStream_t stream) {
    const float* z       = (const float*)d_in[0];   // (B,K,H,W) fp32 0/1
    const float* w_logit = (const float*)d_in[1];   // (K,)
    const float* tau     = (const float*)d_in[2];   // scalar
    float* out = (float*)d_out;                     // (B,)
    unsigned* packw = (unsigned*)d_ws;              // 2 MB, word-major
    float* gLUT = (float*)((char*)d_ws + PACKW_BYTES); // +32 KB

    hipLaunchKernelGGL(pack_kernel, dim3(1025), dim3(256), 0, stream,
                       z, packw, gLUT, w_logit, out);
    hipLaunchKernelGGL(energy_kernel, dim3(2048), dim3(256), 0, stream,
                       packw, gLUT, tau, out);
}